// Round 6
// baseline (811.409 us; speedup 1.0000x reference)
//
#include <hip/hip_runtime.h>
#include <hip/hip_bf16.h>
#include <math.h>
#include <cstdint>

#define FEPS 1e-8f
#define NTHR 256
#define CAND_CAP 4096

#define GRID_KEYS 2048
#define GRID_FIN  8192

// single-level linear-z binning: 2^18 bins of width 1/4096 over [-8, 24)
#define NBINS (1 << 18)
#define NCHUNK 1024          // chunks of 256 bins
#define ZOFF  8.0f
#define ZSCALE 4096.0f
#define ZBINW 0.000244140625f  // 2^-12, exact

// ---------- numeric helpers ----------

// monotonic float -> uint mapping (order-preserving, ascending)
__device__ __forceinline__ uint32_t f2k(float f) {
    uint32_t b = __float_as_uint(f);
    return (b & 0x80000000u) ? ~b : (b | 0x80000000u);
}

// fast path: device logf (faithful ~1ulp)
__device__ __forceinline__ float gum_fast(float u) {
    float t = u + FEPS;
    float a = logf(t);
    float w = -a + FEPS;
    float d = logf(w);
    return -d;
}

// correctly-rounded f32 log via f64 log
__device__ __forceinline__ float logCR(float x) {
    return (float)log((double)x);
}
__device__ __forceinline__ float gum_cr(float u) {
    float t = u + FEPS;
    float a = logCR(t);
    float w = -a + FEPS;
    float d = logCR(w);
    return -d;
}

// exact decision for the 2-way gumbel-softmax argmax:
// out = 1  iff  RN(v1 - v0) > 2^-25
__device__ __forceinline__ float decide_cr(float maskv, float ua, float ub) {
    float G0 = gum_cr(ua);
    float G1 = gum_cr(ub);
    float V1 = maskv + G1;
    float diff = V1 - G0;
    return (diff > 0x1p-25f) ? 1.0f : 0.0f;
}

// fast decision via ratio trick: out=1 iff w0 > exp(2^-25-mv)*w1
// 2 logf instead of 4; CR fallback inside a 1e-4 relative band around the cut.
__device__ __forceinline__ float decide_fast(float mv, float ua, float ub) {
    float w0 = -logf(ua + FEPS) + FEPS;   // w > 0 always
    float w1 = -logf(ub + FEPS) + FEPS;
    float T = (mv != 0.0f) ? 0.36787944f : 1.0f;  // ~exp(2^-25 - mv)
    float rhs = T * w1;
    float q = w0 - rhs;
    if (fabsf(q) > 1e-4f * rhs) return (q > 0.0f) ? 1.0f : 0.0f;
    return decide_cr(mv, ua, ub);
}

__device__ __forceinline__ int zbin(float z) {
    float t = (z + ZOFF) * ZSCALE;
    int b = (int)t;
    b = (b < 0) ? 0 : b;
    b = (b > NBINS - 1) ? (NBINS - 1) : b;
    return b;
}

// ---------- K0: zero hist (1MB) + scalars ----------
__global__ void k_zero(uint32_t* __restrict__ hist, uint32_t* __restrict__ scal,
                       uint32_t* __restrict__ candCount) {
    int i = blockIdx.x * blockDim.x + threadIdx.x;
    int stride = gridDim.x * blockDim.x;
    for (int b = i; b < NBINS; b += stride) hist[b] = 0u;
    if (i < 16) scal[i] = 0u;
    if (i == 0) *candCount = 0u;
}

// ---------- K1: keys (into d_out) + 2^18-bin linear-z GLOBAL histogram ----------
// 2 float4-positions per thread per iteration; 4 independent 16B loads in flight.
__global__ void __launch_bounds__(NTHR) k_keys(
        const float* __restrict__ lg, const float* __restrict__ u1,
        const int* __restrict__ trainp, uint32_t* __restrict__ keys,
        uint32_t* __restrict__ hist, int N) {
    const int tr = *trainp;
    const int n4 = N >> 2;
    const int nth = gridDim.x * NTHR;
    const float4* lg4 = (const float4*)lg;
    const float4* u14 = (const float4*)u1;
    uint4* k4 = (uint4*)keys;

    int p0 = blockIdx.x * NTHR + threadIdx.x;
    while (p0 + nth < n4) {
        const int p1 = p0 + nth;
        float4 m0 = lg4[p0];
        float4 m1 = lg4[p1];
        float4 a0 = u14[p0];
        float4 a1 = u14[p1];
        float z0, z1, z2, z3, z4, z5, z6, z7;
        if (tr) {
            z0 = m0.x + gum_fast(a0.x); z1 = m0.y + gum_fast(a0.y);
            z2 = m0.z + gum_fast(a0.z); z3 = m0.w + gum_fast(a0.w);
            z4 = m1.x + gum_fast(a1.x); z5 = m1.y + gum_fast(a1.y);
            z6 = m1.z + gum_fast(a1.z); z7 = m1.w + gum_fast(a1.w);
        } else {
            z0 = m0.x; z1 = m0.y; z2 = m0.z; z3 = m0.w;
            z4 = m1.x; z5 = m1.y; z6 = m1.z; z7 = m1.w;
        }
        k4[p0] = make_uint4(f2k(z0), f2k(z1), f2k(z2), f2k(z3));
        k4[p1] = make_uint4(f2k(z4), f2k(z5), f2k(z6), f2k(z7));
        atomicAdd(&hist[zbin(z0)], 1u); atomicAdd(&hist[zbin(z1)], 1u);
        atomicAdd(&hist[zbin(z2)], 1u); atomicAdd(&hist[zbin(z3)], 1u);
        atomicAdd(&hist[zbin(z4)], 1u); atomicAdd(&hist[zbin(z5)], 1u);
        atomicAdd(&hist[zbin(z6)], 1u); atomicAdd(&hist[zbin(z7)], 1u);
        p0 += 2 * nth;
    }
    if (p0 < n4) {
        float4 m0 = lg4[p0];
        float4 a0 = u14[p0];
        float z0, z1, z2, z3;
        if (tr) {
            z0 = m0.x + gum_fast(a0.x); z1 = m0.y + gum_fast(a0.y);
            z2 = m0.z + gum_fast(a0.z); z3 = m0.w + gum_fast(a0.w);
        } else { z0 = m0.x; z1 = m0.y; z2 = m0.z; z3 = m0.w; }
        k4[p0] = make_uint4(f2k(z0), f2k(z1), f2k(z2), f2k(z3));
        atomicAdd(&hist[zbin(z0)], 1u); atomicAdd(&hist[zbin(z1)], 1u);
        atomicAdd(&hist[zbin(z2)], 1u); atomicAdd(&hist[zbin(z3)], 1u);
    }
    for (int i = (n4 << 2) + blockIdx.x * NTHR + threadIdx.x; i < N; i += nth) {
        float m = lg[i], u = u1[i];
        float z = tr ? (m + gum_fast(u)) : m;
        keys[i] = f2k(z);
        atomicAdd(&hist[zbin(z)], 1u);
    }
}

// ---------- K2a: chunk partial sums (1024 chunks of 256 bins) ----------
__global__ void __launch_bounds__(NTHR) k_part(
        const uint32_t* __restrict__ hist, uint32_t* __restrict__ part) {
    __shared__ uint32_t red[NTHR];
    const int base = blockIdx.x << 8;
    red[threadIdx.x] = hist[base + threadIdx.x];
    __syncthreads();
    for (int off = NTHR / 2; off; off >>= 1) {
        if (threadIdx.x < off) red[threadIdx.x] += red[threadIdx.x + off];
        __syncthreads();
    }
    if (threadIdx.x == 0) part[blockIdx.x] = red[0];
}

// ---------- K2b: locate threshold bin b1, emit guarded key window [klo,khi] ----------
__global__ void __launch_bounds__(1024) k_scan1(
        const uint32_t* __restrict__ hist, const uint32_t* __restrict__ part,
        const int* __restrict__ kptr, uint32_t* __restrict__ scal) {
    __shared__ uint32_t cs[1024];
    __shared__ uint32_t bs[1024];
    __shared__ int shI[2];
    const int t = threadIdx.x;
    const uint32_t K = (uint32_t)(*kptr);

    // reversed inclusive scan over 1024 chunk partials
    cs[t] = part[1023 - t];
    __syncthreads();
    for (int off = 1; off < 1024; off <<= 1) {
        uint32_t add = (t >= off) ? cs[t - off] : 0u;
        __syncthreads();
        cs[t] += add;
        __syncthreads();
    }
    {
        uint32_t excl = t ? cs[t - 1] : 0u;
        if (excl < K && K <= cs[t]) shI[0] = t;
    }
    __syncthreads();
    const int rp = shI[0];
    const int jc = 1023 - rp;                       // chunk containing rank K
    const uint32_t gt_chunks = rp ? cs[rp - 1] : 0u;
    const uint32_t kk_in = K - gt_chunks;           // rank within chunk (from top)

    // reversed inclusive scan over the 256 bins of chunk jc
    bs[t] = (t < 256) ? hist[(jc << 8) + (255 - t)] : 0u;
    __syncthreads();
    for (int off = 1; off < 1024; off <<= 1) {
        uint32_t add = (t >= off) ? bs[t - off] : 0u;
        __syncthreads();
        bs[t] += add;
        __syncthreads();
    }
    {
        uint32_t excl = t ? bs[t - 1] : 0u;
        if (t < 256 && excl < kk_in && kk_in <= bs[t]) shI[1] = t;
    }
    __syncthreads();
    if (t == 0) {
        const int rq = shI[1];
        const int b1 = (jc << 8) + (255 - rq);      // threshold z-bin
        // exact bin edges in z (b*2^-12 and -8 are exact in f32)
        float elo = (float)b1 * ZBINW - ZOFF;
        float ehi = (float)(b1 + 1) * ZBINW - ZOFF;
        uint32_t klo = (b1 == 0) ? 0u : (f2k(elo) - 64u);
        uint32_t khi = (b1 == NBINS - 1) ? 0xFFFFFFFFu : (f2k(ehi) + 63u);
        scal[3] = klo;
        scal[4] = khi;
    }
}

// ---------- K3: final pass — decide non-window elems, collect candidates, count caw ----------
// u2 is INTERLEAVED per element: pair for element i is (u2[2i], u2[2i+1]).
// keys live in d_out; read key then overwrite with result.
__global__ void __launch_bounds__(NTHR) k_final(
        uint32_t* __restrict__ keys /* == (uint32_t*)d_out */,
        const float* __restrict__ u2, const int* __restrict__ trainp,
        const uint32_t* __restrict__ scal_ro,
        uint32_t* __restrict__ scal, uint32_t* __restrict__ candIdx,
        uint32_t* __restrict__ candCount, int N) {
    __shared__ uint32_t red[NTHR];
    const uint32_t klo = scal_ro[3], khi = scal_ro[4];
    const int tr = *trainp;
    const int n4 = N >> 2;
    const int nth = gridDim.x * NTHR;
    const uint4* kr4 = (const uint4*)keys;
    const float4* u24 = (const float4*)u2;
    float* outf = (float*)keys;
    uint32_t gt = 0;   // count of keys strictly above window (sure-selected)

    int p0 = blockIdx.x * NTHR + threadIdx.x;
    while (p0 + nth < n4) {
        const int p1 = p0 + nth;
        uint4 kk0 = kr4[p0];
        uint4 kk1 = kr4[p1];
        float4 ua0, ub0, ua1, ub1;
        if (tr) {
            ua0 = u24[2 * p0]; ub0 = u24[2 * p0 + 1];
            ua1 = u24[2 * p1]; ub1 = u24[2 * p1 + 1];
        }
        uint32_t ks[8] = {kk0.x, kk0.y, kk0.z, kk0.w, kk1.x, kk1.y, kk1.z, kk1.w};
        float uu[16];
        if (tr) {
            uu[0] = ua0.x; uu[1] = ua0.y; uu[2] = ua0.z; uu[3] = ua0.w;
            uu[4] = ub0.x; uu[5] = ub0.y; uu[6] = ub0.z; uu[7] = ub0.w;
            uu[8] = ua1.x; uu[9] = ua1.y; uu[10] = ua1.z; uu[11] = ua1.w;
            uu[12] = ub1.x; uu[13] = ub1.y; uu[14] = ub1.z; uu[15] = ub1.w;
        }
        float res[8];
        bool inw[8];
        bool anyw = false;
        #pragma unroll
        for (int j = 0; j < 8; j++) {
            inw[j] = (ks[j] >= klo) && (ks[j] <= khi);
            anyw |= inw[j];
            gt += (ks[j] > khi) ? 1u : 0u;
        }
        #pragma unroll
        for (int j = 0; j < 8; j++) {
            const int half = j >> 2, e = j & 3;
            float mv = (ks[j] > khi) ? 1.0f : 0.0f;
            // interleaved pair: a = uu[half*8 + 2e], b = uu[half*8 + 2e + 1]
            float ua = uu[half * 8 + 2 * e];
            float ub = uu[half * 8 + 2 * e + 1];
            res[j] = (tr && !inw[j]) ? decide_fast(mv, ua, ub) : mv;
        }
        if (!anyw) {
            ((float4*)outf)[p0] = make_float4(res[0], res[1], res[2], res[3]);
            ((float4*)outf)[p1] = make_float4(res[4], res[5], res[6], res[7]);
        } else {
            #pragma unroll
            for (int j = 0; j < 8; j++) {
                const int idx = ((j < 4) ? p0 : p1) * 4 + (j & 3);
                if (inw[j]) {
                    uint32_t p = atomicAdd(candCount, 1u);
                    if (p < CAND_CAP) candIdx[p] = (uint32_t)idx;
                } else {
                    outf[idx] = res[j];
                }
            }
        }
        p0 += 2 * nth;
    }
    if (p0 < n4) {
        uint4 kk = kr4[p0];
        float4 ua, ub;
        if (tr) { ua = u24[2 * p0]; ub = u24[2 * p0 + 1]; }
        uint32_t ks[4] = {kk.x, kk.y, kk.z, kk.w};
        float pa[4] = {ua.x, ua.z, ub.x, ub.z};
        float pb[4] = {ua.y, ua.w, ub.y, ub.w};
        #pragma unroll
        for (int j = 0; j < 4; j++) {
            uint32_t kx = ks[j];
            gt += (kx > khi) ? 1u : 0u;
            if (kx >= klo && kx <= khi) {
                uint32_t p = atomicAdd(candCount, 1u);
                if (p < CAND_CAP) candIdx[p] = (uint32_t)(4 * p0 + j);
            } else {
                float mv = (kx > khi) ? 1.0f : 0.0f;
                outf[4 * p0 + j] = tr ? decide_fast(mv, pa[j], pb[j]) : mv;
            }
        }
    }
    for (int i = (n4 << 2) + blockIdx.x * NTHR + threadIdx.x; i < N; i += nth) {
        uint32_t kx = keys[i];
        gt += (kx > khi) ? 1u : 0u;
        if (kx >= klo && kx <= khi) {
            uint32_t p = atomicAdd(candCount, 1u);
            if (p < CAND_CAP) candIdx[p] = (uint32_t)i;
            continue;
        }
        float mv = (kx > khi) ? 1.0f : 0.0f;
        outf[i] = tr ? decide_fast(mv, u2[2 * i], u2[2 * i + 1]) : mv;
    }

    // exact count-above-window -> scal[5]
    red[threadIdx.x] = gt;
    __syncthreads();
    for (int off = NTHR / 2; off; off >>= 1) {
        if (threadIdx.x < off) red[threadIdx.x] += red[threadIdx.x + off];
        __syncthreads();
    }
    if (threadIdx.x == 0 && red[0]) atomicAdd(&scal[5], red[0]);
}

// ---------- K4: refine window candidates exactly (CR log, sort, select) ----------
__global__ void __launch_bounds__(NTHR) k_refine(
        const float* __restrict__ lg, const float* __restrict__ u1,
        const float* __restrict__ u2, const int* __restrict__ kptr,
        const int* __restrict__ trainp, const uint32_t* __restrict__ scal,
        const uint32_t* __restrict__ candIdx, const uint32_t* __restrict__ candCount,
        float* __restrict__ out) {
    __shared__ float zs[CAND_CAP];
    __shared__ int is[CAND_CAP];
    const int tr = *trainp;
    int n = (int)(*candCount);
    if (n > CAND_CAP) n = CAND_CAP;
    int npow2 = 64;
    while (npow2 < n) npow2 <<= 1;

    for (int e = threadIdx.x; e < npow2; e += NTHR) {
        if (e < n) {
            int i = (int)candIdx[e];
            float m = lg[i];
            zs[e] = tr ? (m + gum_cr(u1[i])) : m;
            is[e] = i;
        } else {
            zs[e] = -INFINITY;
            is[e] = 0x40000000 + e;
        }
    }
    __syncthreads();

    // bitonic sort: descending by z, ascending index on ties (matches lax.top_k)
    for (int size = 2; size <= npow2; size <<= 1) {
        for (int str = size >> 1; str > 0; str >>= 1) {
            for (int e = threadIdx.x; e < npow2; e += NTHR) {
                int p = e ^ str;
                if (p > e) {
                    float za = zs[e], zb = zs[p];
                    int ia = is[e], ib = is[p];
                    bool aBefore = (za > zb) || (za == zb && ia < ib);
                    bool descBlock = ((e & size) == 0);
                    if (descBlock ? !aBefore : aBefore) {
                        zs[e] = zb; zs[p] = za;
                        is[e] = ib; is[p] = ia;
                    }
                }
            }
            __syncthreads();
        }
    }

    const int K = *kptr;
    const int caw = (int)scal[5];
    const int R = K - caw;   // how many window elements are selected
    for (int e = threadIdx.x; e < n; e += NTHR) {
        int i = is[e];
        float mv = (e < R) ? 1.0f : 0.0f;
        out[i] = tr ? decide_cr(mv, u2[2 * i], u2[2 * i + 1]) : mv;
    }
}

// ---------- launcher ----------
extern "C" void kernel_launch(void* const* d_in, const int* in_sizes, int n_in,
                              void* d_out, int out_size, void* d_ws, size_t ws_size,
                              hipStream_t stream) {
    const float* lg = (const float*)d_in[0];
    const float* u1 = (const float*)d_in[1];
    const float* u2 = (const float*)d_in[2];
    const int* kptr = (const int*)d_in[3];
    const int* trainp = (const int*)d_in[4];
    float* out = (float*)d_out;
    const int N = in_sizes[0];

    uint32_t* keys = (uint32_t*)d_out;   // staged in d_out, overwritten by results

    // workspace (~1.1 MB)
    uint32_t* hist = (uint32_t*)d_ws;            // 2^18
    uint32_t* part = hist + NBINS;               // 1024
    uint32_t* scal = part + NCHUNK;              // 16
    uint32_t* candCount = scal + 16;             // 1
    uint32_t* candIdx = candCount + 1;           // CAND_CAP

    k_zero<<<dim3(256), dim3(NTHR), 0, stream>>>(hist, scal, candCount);
    k_keys<<<dim3(GRID_KEYS), dim3(NTHR), 0, stream>>>(lg, u1, trainp, keys, hist, N);
    k_part<<<dim3(NCHUNK), dim3(NTHR), 0, stream>>>(hist, part);
    k_scan1<<<dim3(1), dim3(1024), 0, stream>>>(hist, part, kptr, scal);
    k_final<<<dim3(GRID_FIN), dim3(NTHR), 0, stream>>>(keys, u2, trainp, scal, scal,
                                                       candIdx, candCount, N);
    k_refine<<<dim3(1), dim3(NTHR), 0, stream>>>(lg, u1, u2, kptr, trainp, scal,
                                                 candIdx, candCount, out);
}

// Round 7
// 184.078 us; speedup vs baseline: 4.4080x; 4.4080x over previous
//
#include <hip/hip_runtime.h>
#include <hip/hip_bf16.h>
#include <math.h>
#include <cstdint>

#define FEPS 1e-8f
#define NTHR 256
#define CAND_CAP 4096
#define NREP 32            // replicated coarse histograms

#define GRID_KEYS 2048
#define GRID_H2   4096
#define GRID_FIN  8192
#define GRID_PART 1024

// linear-z binning for pass 1: 4096 bins over [-8, 24), width 1/128
#define ZMIN 8.0f
#define ZSCALE 128.0f
#define ZBINW 0.0078125f   // 1/128, exact in f32

// ---------- numeric helpers ----------

__device__ __forceinline__ uint32_t f2k(float f) {
    uint32_t b = __float_as_uint(f);
    return (b & 0x80000000u) ? ~b : (b | 0x80000000u);
}

__device__ __forceinline__ float gum_fast(float u) {
    float t = u + FEPS;
    float a = logf(t);
    float w = -a + FEPS;
    float d = logf(w);
    return -d;
}

__device__ __forceinline__ float logCR(float x) {
    return (float)log((double)x);
}
__device__ __forceinline__ float gum_cr(float u) {
    float t = u + FEPS;
    float a = logCR(t);
    float w = -a + FEPS;
    float d = logCR(w);
    return -d;
}

// exact decision: out = 1 iff RN(v1 - v0) > 2^-25
__device__ __forceinline__ float decide_cr(float maskv, float ua, float ub) {
    float G0 = gum_cr(ua);
    float G1 = gum_cr(ub);
    float V1 = maskv + G1;
    float diff = V1 - G0;
    return (diff > 0x1p-25f) ? 1.0f : 0.0f;
}

// ratio trick: out=1 iff w0 > exp(2^-25-mv)*w1; CR fallback in 1e-4 band
__device__ __forceinline__ float decide_fast(float mv, float ua, float ub) {
    float w0 = -logf(ua + FEPS) + FEPS;
    float w1 = -logf(ub + FEPS) + FEPS;
    float T = (mv != 0.0f) ? 0.36787944f : 1.0f;
    float rhs = T * w1;
    float q = w0 - rhs;
    if (fabsf(q) > 1e-4f * rhs) return (q > 0.0f) ? 1.0f : 0.0f;
    return decide_cr(mv, ua, ub);
}

__device__ __forceinline__ int zbin(float z) {
    float t = (z + ZMIN) * ZSCALE;
    int b = (int)t;
    if (b < 0) b = 0;
    if (b > 4095) b = 4095;
    return b;
}

// ---------- K0: zero workspace ----------
__global__ void k_zero(uint32_t* __restrict__ hist1r, uint32_t* __restrict__ hist2,
                       uint32_t* __restrict__ scal, uint32_t* __restrict__ candCount) {
    int i = blockIdx.x * blockDim.x + threadIdx.x;
    int stride = gridDim.x * blockDim.x;
    for (int b = i; b < NREP * 4096; b += stride) hist1r[b] = 0u;
    for (int b = i; b < (1 << 20); b += stride) hist2[b] = 0u;
    if (i < 16) scal[i] = 0u;
    if (i == 0) *candCount = 0u;
}

// ---------- K1: keys (into d_out) + LDS hist -> replicated global merge ----------
__global__ void __launch_bounds__(NTHR) k_keys(
        const float* __restrict__ lg, const float* __restrict__ u1,
        const int* __restrict__ trainp, uint32_t* __restrict__ keys,
        uint32_t* __restrict__ hist1r, int N) {
    __shared__ uint32_t h[4096];
    for (int b = threadIdx.x; b < 4096; b += NTHR) h[b] = 0u;
    __syncthreads();
    const int tr = *trainp;
    const int n4 = N >> 2;
    const int nth = gridDim.x * NTHR;
    const float4* lg4 = (const float4*)lg;
    const float4* u14 = (const float4*)u1;
    uint4* k4 = (uint4*)keys;

    int p0 = blockIdx.x * NTHR + threadIdx.x;
    while (p0 + nth < n4) {
        const int p1 = p0 + nth;
        float4 m0 = lg4[p0];
        float4 m1 = lg4[p1];
        float4 a0 = u14[p0];
        float4 a1 = u14[p1];
        float z0, z1, z2, z3, z4, z5, z6, z7;
        if (tr) {
            z0 = m0.x + gum_fast(a0.x); z1 = m0.y + gum_fast(a0.y);
            z2 = m0.z + gum_fast(a0.z); z3 = m0.w + gum_fast(a0.w);
            z4 = m1.x + gum_fast(a1.x); z5 = m1.y + gum_fast(a1.y);
            z6 = m1.z + gum_fast(a1.z); z7 = m1.w + gum_fast(a1.w);
        } else {
            z0 = m0.x; z1 = m0.y; z2 = m0.z; z3 = m0.w;
            z4 = m1.x; z5 = m1.y; z6 = m1.z; z7 = m1.w;
        }
        k4[p0] = make_uint4(f2k(z0), f2k(z1), f2k(z2), f2k(z3));
        k4[p1] = make_uint4(f2k(z4), f2k(z5), f2k(z6), f2k(z7));
        atomicAdd(&h[zbin(z0)], 1u); atomicAdd(&h[zbin(z1)], 1u);
        atomicAdd(&h[zbin(z2)], 1u); atomicAdd(&h[zbin(z3)], 1u);
        atomicAdd(&h[zbin(z4)], 1u); atomicAdd(&h[zbin(z5)], 1u);
        atomicAdd(&h[zbin(z6)], 1u); atomicAdd(&h[zbin(z7)], 1u);
        p0 += 2 * nth;
    }
    if (p0 < n4) {
        float4 m0 = lg4[p0];
        float4 a0 = u14[p0];
        float z0, z1, z2, z3;
        if (tr) {
            z0 = m0.x + gum_fast(a0.x); z1 = m0.y + gum_fast(a0.y);
            z2 = m0.z + gum_fast(a0.z); z3 = m0.w + gum_fast(a0.w);
        } else { z0 = m0.x; z1 = m0.y; z2 = m0.z; z3 = m0.w; }
        k4[p0] = make_uint4(f2k(z0), f2k(z1), f2k(z2), f2k(z3));
        atomicAdd(&h[zbin(z0)], 1u); atomicAdd(&h[zbin(z1)], 1u);
        atomicAdd(&h[zbin(z2)], 1u); atomicAdd(&h[zbin(z3)], 1u);
    }
    for (int i = (n4 << 2) + blockIdx.x * NTHR + threadIdx.x; i < N; i += nth) {
        float m = lg[i], u = u1[i];
        float z = tr ? (m + gum_fast(u)) : m;
        keys[i] = f2k(z);
        atomicAdd(&h[zbin(z)], 1u);
    }
    __syncthreads();
    // merge into this block's replica: contention per line reduced NREP x
    uint32_t* rep = hist1r + (uint32_t)(blockIdx.x & (NREP - 1)) * 4096u;
    for (int b = threadIdx.x; b < 4096; b += NTHR) {
        uint32_t v = h[b];
        if (v) atomicAdd(&rep[b], v);
    }
}

// ---------- K2: sum replicas, scan 4096 bins from top, find bin b1 -> keybase ----------
__global__ void __launch_bounds__(1024) k_scan1(
        const uint32_t* __restrict__ hist1r, const int* __restrict__ kptr,
        uint32_t* __restrict__ scal) {
    __shared__ uint32_t vals[4096];
    __shared__ uint32_t cnt[1024];
    const int t = threadIdx.x;
    uint32_t loc = 0;
    for (int j = 0; j < 4; j++) {
        const int bin = 4095 - (t * 4 + j);
        uint32_t v = 0;
        #pragma unroll
        for (int r = 0; r < NREP; r++) v += hist1r[r * 4096 + bin];
        vals[t * 4 + j] = v;
        loc += v;
    }
    cnt[t] = loc;
    __syncthreads();
    for (int off = 1; off < 1024; off <<= 1) {
        uint32_t add = (t >= off) ? cnt[t - off] : 0u;
        __syncthreads();
        cnt[t] += add;
        __syncthreads();
    }
    const uint32_t K = (uint32_t)(*kptr);
    uint32_t excl = (t > 0) ? cnt[t - 1] : 0u;
    uint32_t incl = cnt[t];
    if (excl < K && K <= incl) {
        uint32_t c = excl;
        for (int j = 0; j < 4; j++) {
            uint32_t v = vals[t * 4 + j];
            if (K <= c + v) {
                int b1 = 4095 - (t * 4 + j);             // k-th element in this z-bin
                float edge = (float)b1 * ZBINW - ZMIN;   // lower z-edge, exact
                uint32_t kb = f2k(edge) - 2048u;         // margin for bin-edge fuzz
                scal[0] = kb;                            // keybase
                break;
            }
            c += v;
        }
    }
}

// ---------- K3: 1-ulp histogram of keys in [kb, kb+2^20); exact GT count ----------
__global__ void __launch_bounds__(NTHR) k_hist2(
        const uint32_t* __restrict__ keys, const uint32_t* __restrict__ scal,
        uint32_t* __restrict__ hist2, uint32_t* __restrict__ gtOut, int N) {
    __shared__ uint32_t red[NTHR];
    const uint32_t kb = scal[0];
    const uint32_t hiB = kb + (1u << 20);
    const int n4 = N >> 2;
    const int nth = gridDim.x * NTHR;
    const uint4* k4 = (const uint4*)keys;
    uint32_t gt = 0;

    int p0 = blockIdx.x * NTHR + threadIdx.x;
    while (p0 + 3 * nth < n4) {
        uint4 kk0 = k4[p0];
        uint4 kk1 = k4[p0 + nth];
        uint4 kk2 = k4[p0 + 2 * nth];
        uint4 kk3 = k4[p0 + 3 * nth];
        uint32_t ks[16] = {kk0.x, kk0.y, kk0.z, kk0.w, kk1.x, kk1.y, kk1.z, kk1.w,
                           kk2.x, kk2.y, kk2.z, kk2.w, kk3.x, kk3.y, kk3.z, kk3.w};
        #pragma unroll
        for (int j = 0; j < 16; j++) {
            uint32_t kx = ks[j];
            if (kx >= hiB) gt++;
            else if (kx >= kb) atomicAdd(&hist2[kx - kb], 1u);
        }
        p0 += 4 * nth;
    }
    while (p0 < n4) {
        uint4 kk = k4[p0];
        uint32_t ks[4] = {kk.x, kk.y, kk.z, kk.w};
        #pragma unroll
        for (int j = 0; j < 4; j++) {
            uint32_t kx = ks[j];
            if (kx >= hiB) gt++;
            else if (kx >= kb) atomicAdd(&hist2[kx - kb], 1u);
        }
        p0 += nth;
    }
    for (int i = (n4 << 2) + blockIdx.x * NTHR + threadIdx.x; i < N; i += nth) {
        uint32_t kx = keys[i];
        if (kx >= hiB) gt++;
        else if (kx >= kb) atomicAdd(&hist2[kx - kb], 1u);
    }
    red[threadIdx.x] = gt;
    __syncthreads();
    for (int off = NTHR / 2; off; off >>= 1) {
        if (threadIdx.x < off) red[threadIdx.x] += red[threadIdx.x + off];
        __syncthreads();
    }
    if (threadIdx.x == 0 && red[0]) atomicAdd(gtOut, red[0]);
}

// ---------- K4a: chunk partial sums of hist2 (1024 chunks of 1024) ----------
__global__ void __launch_bounds__(NTHR) k_part(
        const uint32_t* __restrict__ hist2, uint32_t* __restrict__ part) {
    __shared__ uint32_t red[NTHR];
    uint32_t sum = 0;
    const int base = blockIdx.x << 10;
    for (int j = threadIdx.x; j < 1024; j += NTHR) sum += hist2[base + j];
    red[threadIdx.x] = sum;
    __syncthreads();
    for (int off = NTHR / 2; off; off >>= 1) {
        if (threadIdx.x < off) red[threadIdx.x] += red[threadIdx.x + off];
        __syncthreads();
    }
    if (threadIdx.x == 0) part[blockIdx.x] = red[0];
}

// ---------- K4b: exact threshold offset, window [klo,khi], count above window ----------
__global__ void __launch_bounds__(1024) k_scan2(
        const uint32_t* __restrict__ hist2, const uint32_t* __restrict__ part,
        const int* __restrict__ kptr, uint32_t* __restrict__ scal) {
    __shared__ uint32_t cs[1024];
    __shared__ uint32_t bs[1024];
    __shared__ uint32_t red[1024];
    __shared__ int shI[4];
    const int t = threadIdx.x;
    const uint32_t kb = scal[0];
    const uint32_t GT = scal[1];
    const uint32_t kk1 = (uint32_t)(*kptr) - GT;

    cs[t] = part[1023 - t];
    __syncthreads();
    for (int off = 1; off < 1024; off <<= 1) {
        uint32_t add = (t >= off) ? cs[t - off] : 0u;
        __syncthreads();
        cs[t] += add;
        __syncthreads();
    }
    {
        uint32_t excl = t ? cs[t - 1] : 0u;
        if (excl < kk1 && kk1 <= cs[t]) shI[0] = t;
    }
    __syncthreads();
    const int rp = shI[0];
    const int jc = 1023 - rp;
    const uint32_t gt_chunks = rp ? cs[rp - 1] : 0u;
    const uint32_t kk_in = kk1 - gt_chunks;

    bs[t] = hist2[(jc << 10) + (1023 - t)];
    __syncthreads();
    for (int off = 1; off < 1024; off <<= 1) {
        uint32_t add = (t >= off) ? bs[t - off] : 0u;
        __syncthreads();
        bs[t] += add;
        __syncthreads();
    }
    {
        uint32_t excl = t ? bs[t - 1] : 0u;
        if (excl < kk_in && kk_in <= bs[t]) shI[1] = t;
    }
    __syncthreads();
    const int rq = shI[1];
    const int b2 = (jc << 10) + (1023 - rq);

    int W = 64;
    int lo = 0, hi = 0;
    uint32_t caw = 0;
    while (true) {
        lo = b2 - W; if (lo < 0) lo = 0;
        hi = b2 + W; if (hi > 0xFFFFF) hi = 0xFFFFF;
        uint32_t v = 0;
        for (int b = lo + t; b <= hi; b += 1024) v += hist2[b];
        red[t] = v;
        __syncthreads();
        for (int off = 512; off; off >>= 1) {
            if (t < off) red[t] += red[t + off];
            __syncthreads();
        }
        uint32_t nW = red[0];
        __syncthreads();
        if (nW <= 3500u || W == 0) {
            const int ch = hi >> 10;
            const int chend = (ch << 10) + 1023;
            uint32_t v2 = 0;
            for (int b = hi + 1 + t; b <= chend; b += 1024) v2 += hist2[b];
            red[t] = v2;
            __syncthreads();
            for (int off = 512; off; off >>= 1) {
                if (t < off) red[t] += red[t + off];
                __syncthreads();
            }
            uint32_t inpart = red[0];
            __syncthreads();
            const int rpch = 1023 - ch;
            const uint32_t sufExcl = rpch ? cs[rpch - 1] : 0u;
            caw = GT + sufExcl + inpart;
            break;
        }
        W >>= 1;
    }
    if (t == 0) {
        scal[3] = kb + (uint32_t)lo;  // klo
        scal[4] = kb + (uint32_t)hi;  // khi
        scal[5] = caw;
    }
}

// ---------- K5: final pass — ratio-trick decisions, collect window candidates ----------
// u2 is INTERLEAVED: pair for element i is (u2[2i], u2[2i+1]).
__global__ void __launch_bounds__(NTHR) k_final(
        uint32_t* __restrict__ keys /* == (uint32_t*)d_out */,
        const float* __restrict__ u2, const int* __restrict__ trainp,
        const uint32_t* __restrict__ scal,
        uint32_t* __restrict__ candIdx, uint32_t* __restrict__ candCount, int N) {
    const uint32_t klo = scal[3], khi = scal[4];
    const int tr = *trainp;
    const int n4 = N >> 2;
    const int nth = gridDim.x * NTHR;
    const uint4* kr4 = (const uint4*)keys;
    const float4* u24 = (const float4*)u2;
    float* outf = (float*)keys;

    int p0 = blockIdx.x * NTHR + threadIdx.x;
    while (p0 + nth < n4) {
        const int p1 = p0 + nth;
        uint4 kk0 = kr4[p0];
        uint4 kk1 = kr4[p1];
        float4 ua0, ub0, ua1, ub1;
        if (tr) {
            ua0 = u24[2 * p0]; ub0 = u24[2 * p0 + 1];
            ua1 = u24[2 * p1]; ub1 = u24[2 * p1 + 1];
        }
        uint32_t ks[8] = {kk0.x, kk0.y, kk0.z, kk0.w, kk1.x, kk1.y, kk1.z, kk1.w};
        float uu[16];
        if (tr) {
            uu[0] = ua0.x; uu[1] = ua0.y; uu[2] = ua0.z; uu[3] = ua0.w;
            uu[4] = ub0.x; uu[5] = ub0.y; uu[6] = ub0.z; uu[7] = ub0.w;
            uu[8] = ua1.x; uu[9] = ua1.y; uu[10] = ua1.z; uu[11] = ua1.w;
            uu[12] = ub1.x; uu[13] = ub1.y; uu[14] = ub1.z; uu[15] = ub1.w;
        }
        float res[8];
        bool inw[8];
        bool anyw = false;
        #pragma unroll
        for (int j = 0; j < 8; j++) {
            inw[j] = (ks[j] >= klo) && (ks[j] <= khi);
            anyw |= inw[j];
        }
        #pragma unroll
        for (int j = 0; j < 8; j++) {
            const int half = j >> 2, e = j & 3;
            float mv = (ks[j] > khi) ? 1.0f : 0.0f;
            float ua = uu[half * 8 + 2 * e];
            float ub = uu[half * 8 + 2 * e + 1];
            res[j] = (tr && !inw[j]) ? decide_fast(mv, ua, ub) : mv;
        }
        if (!anyw) {
            ((float4*)outf)[p0] = make_float4(res[0], res[1], res[2], res[3]);
            ((float4*)outf)[p1] = make_float4(res[4], res[5], res[6], res[7]);
        } else {
            #pragma unroll
            for (int j = 0; j < 8; j++) {
                const int idx = ((j < 4) ? p0 : p1) * 4 + (j & 3);
                if (inw[j]) {
                    uint32_t p = atomicAdd(candCount, 1u);
                    if (p < CAND_CAP) candIdx[p] = (uint32_t)idx;
                } else {
                    outf[idx] = res[j];
                }
            }
        }
        p0 += 2 * nth;
    }
    if (p0 < n4) {
        uint4 kk = kr4[p0];
        float4 ua, ub;
        if (tr) { ua = u24[2 * p0]; ub = u24[2 * p0 + 1]; }
        uint32_t ks[4] = {kk.x, kk.y, kk.z, kk.w};
        float pa[4] = {ua.x, ua.z, ub.x, ub.z};
        float pb[4] = {ua.y, ua.w, ub.y, ub.w};
        #pragma unroll
        for (int j = 0; j < 4; j++) {
            uint32_t kx = ks[j];
            if (kx >= klo && kx <= khi) {
                uint32_t p = atomicAdd(candCount, 1u);
                if (p < CAND_CAP) candIdx[p] = (uint32_t)(4 * p0 + j);
            } else {
                float mv = (kx > khi) ? 1.0f : 0.0f;
                outf[4 * p0 + j] = tr ? decide_fast(mv, pa[j], pb[j]) : mv;
            }
        }
    }
    for (int i = (n4 << 2) + blockIdx.x * NTHR + threadIdx.x; i < N; i += nth) {
        uint32_t kx = keys[i];
        if (kx >= klo && kx <= khi) {
            uint32_t p = atomicAdd(candCount, 1u);
            if (p < CAND_CAP) candIdx[p] = (uint32_t)i;
            continue;
        }
        float mv = (kx > khi) ? 1.0f : 0.0f;
        outf[i] = tr ? decide_fast(mv, u2[2 * i], u2[2 * i + 1]) : mv;
    }
}

// ---------- K6: refine window candidates exactly (CR log, sort, select) ----------
__global__ void __launch_bounds__(NTHR) k_refine(
        const float* __restrict__ lg, const float* __restrict__ u1,
        const float* __restrict__ u2, const int* __restrict__ kptr,
        const int* __restrict__ trainp, const uint32_t* __restrict__ scal,
        const uint32_t* __restrict__ candIdx, const uint32_t* __restrict__ candCount,
        float* __restrict__ out) {
    __shared__ float zs[CAND_CAP];
    __shared__ int is[CAND_CAP];
    const int tr = *trainp;
    int n = (int)(*candCount);
    if (n > CAND_CAP) n = CAND_CAP;
    int npow2 = 64;
    while (npow2 < n) npow2 <<= 1;

    for (int e = threadIdx.x; e < npow2; e += NTHR) {
        if (e < n) {
            int i = (int)candIdx[e];
            float m = lg[i];
            zs[e] = tr ? (m + gum_cr(u1[i])) : m;
            is[e] = i;
        } else {
            zs[e] = -INFINITY;
            is[e] = 0x40000000 + e;
        }
    }
    __syncthreads();

    for (int size = 2; size <= npow2; size <<= 1) {
        for (int str = size >> 1; str > 0; str >>= 1) {
            for (int e = threadIdx.x; e < npow2; e += NTHR) {
                int p = e ^ str;
                if (p > e) {
                    float za = zs[e], zb = zs[p];
                    int ia = is[e], ib = is[p];
                    bool aBefore = (za > zb) || (za == zb && ia < ib);
                    bool descBlock = ((e & size) == 0);
                    if (descBlock ? !aBefore : aBefore) {
                        zs[e] = zb; zs[p] = za;
                        is[e] = ib; is[p] = ia;
                    }
                }
            }
            __syncthreads();
        }
    }

    const int K = *kptr;
    const int caw = (int)scal[5];
    const int R = K - caw;
    for (int e = threadIdx.x; e < n; e += NTHR) {
        int i = is[e];
        float mv = (e < R) ? 1.0f : 0.0f;
        out[i] = tr ? decide_cr(mv, u2[2 * i], u2[2 * i + 1]) : mv;
    }
}

// ---------- launcher ----------
extern "C" void kernel_launch(void* const* d_in, const int* in_sizes, int n_in,
                              void* d_out, int out_size, void* d_ws, size_t ws_size,
                              hipStream_t stream) {
    const float* lg = (const float*)d_in[0];
    const float* u1 = (const float*)d_in[1];
    const float* u2 = (const float*)d_in[2];
    const int* kptr = (const int*)d_in[3];
    const int* trainp = (const int*)d_in[4];
    float* out = (float*)d_out;
    const int N = in_sizes[0];

    uint32_t* keys = (uint32_t*)d_out;   // staged in d_out, overwritten by results

    // workspace (~4.7 MB)
    uint32_t* hist1r = (uint32_t*)d_ws;          // NREP * 4096
    uint32_t* hist2 = hist1r + NREP * 4096;      // 1<<20
    uint32_t* part = hist2 + (1u << 20);         // 1024
    uint32_t* scal = part + 1024;                // 16
    uint32_t* candCount = scal + 16;             // 1
    uint32_t* candIdx = candCount + 1;           // CAND_CAP

    k_zero<<<dim3(2048), dim3(NTHR), 0, stream>>>(hist1r, hist2, scal, candCount);
    k_keys<<<dim3(GRID_KEYS), dim3(NTHR), 0, stream>>>(lg, u1, trainp, keys, hist1r, N);
    k_scan1<<<dim3(1), dim3(1024), 0, stream>>>(hist1r, kptr, scal);
    k_hist2<<<dim3(GRID_H2), dim3(NTHR), 0, stream>>>(keys, scal, hist2, &scal[1], N);
    k_part<<<dim3(GRID_PART), dim3(NTHR), 0, stream>>>(hist2, part);
    k_scan2<<<dim3(1), dim3(1024), 0, stream>>>(hist2, part, kptr, scal);
    k_final<<<dim3(GRID_FIN), dim3(NTHR), 0, stream>>>(keys, u2, trainp, scal,
                                                       candIdx, candCount, N);
    k_refine<<<dim3(1), dim3(NTHR), 0, stream>>>(lg, u1, u2, kptr, trainp, scal,
                                                 candIdx, candCount, out);
}

// Round 8
// 183.218 us; speedup vs baseline: 4.4286x; 1.0047x over previous
//
#include <hip/hip_runtime.h>
#include <hip/hip_bf16.h>
#include <math.h>
#include <cstdint>

#define FEPS 1e-8f
#define NTHR 256
#define CAND_CAP 4096
#define NREP 32            // replicated coarse histograms

#define GRID_KEYS 2048
#define GRID_H2   4096
#define GRID_FIN  8192
#define GRID_PART 1024

// linear-z binning for pass 1: 4096 bins over [-8, 24), width 1/128
#define ZMIN 8.0f
#define ZSCALE 128.0f
#define ZBINW 0.0078125f   // 1/128, exact in f32

// ---------- numeric helpers ----------

__device__ __forceinline__ uint32_t f2k(float f) {
    uint32_t b = __float_as_uint(f);
    return (b & 0x80000000u) ? ~b : (b | 0x80000000u);
}

__device__ __forceinline__ float gum_fast(float u) {
    float t = u + FEPS;
    float a = logf(t);
    float w = -a + FEPS;
    float d = logf(w);
    return -d;
}

__device__ __forceinline__ float logCR(float x) {
    return (float)log((double)x);
}
__device__ __forceinline__ float gum_cr(float u) {
    float t = u + FEPS;
    float a = logCR(t);
    float w = -a + FEPS;
    float d = logCR(w);
    return -d;
}

// exact decision: out = 1 iff RN(v1 - v0) > 2^-25
__device__ __forceinline__ float decide_cr(float maskv, float ua, float ub) {
    float G0 = gum_cr(ua);
    float G1 = gum_cr(ub);
    float V1 = maskv + G1;
    float diff = V1 - G0;
    return (diff > 0x1p-25f) ? 1.0f : 0.0f;
}

// ratio trick: out=1 iff w0 > exp(2^-25-mv)*w1; CR fallback in 1e-4 band
__device__ __forceinline__ float decide_fast(float mv, float ua, float ub) {
    float w0 = -logf(ua + FEPS) + FEPS;
    float w1 = -logf(ub + FEPS) + FEPS;
    float T = (mv != 0.0f) ? 0.36787944f : 1.0f;
    float rhs = T * w1;
    float q = w0 - rhs;
    if (fabsf(q) > 1e-4f * rhs) return (q > 0.0f) ? 1.0f : 0.0f;
    return decide_cr(mv, ua, ub);
}

__device__ __forceinline__ int zbin(float z) {
    float t = (z + ZMIN) * ZSCALE;
    int b = (int)t;
    if (b < 0) b = 0;
    if (b > 4095) b = 4095;
    return b;
}

// ---------- K0: zero workspace ----------
__global__ void k_zero(uint32_t* __restrict__ hist1r, uint32_t* __restrict__ hist2,
                       uint32_t* __restrict__ scal, uint32_t* __restrict__ candCount) {
    int i = blockIdx.x * blockDim.x + threadIdx.x;
    int stride = gridDim.x * blockDim.x;
    for (int b = i; b < NREP * 4096; b += stride) hist1r[b] = 0u;
    for (int b = i; b < (1 << 20); b += stride) hist2[b] = 0u;
    if (i < 16) scal[i] = 0u;
    if (i == 0) *candCount = 0u;
}

// ---------- K1: keys (into d_out) + LDS hist -> replicated global merge ----------
__global__ void __launch_bounds__(NTHR) k_keys(
        const float* __restrict__ lg, const float* __restrict__ u1,
        const int* __restrict__ trainp, uint32_t* __restrict__ keys,
        uint32_t* __restrict__ hist1r, int N) {
    __shared__ uint32_t h[4096];
    for (int b = threadIdx.x; b < 4096; b += NTHR) h[b] = 0u;
    __syncthreads();
    const int tr = *trainp;
    const int n4 = N >> 2;
    const int nth = gridDim.x * NTHR;
    const float4* lg4 = (const float4*)lg;
    const float4* u14 = (const float4*)u1;
    uint4* k4 = (uint4*)keys;

    int p0 = blockIdx.x * NTHR + threadIdx.x;
    while (p0 + nth < n4) {
        const int p1 = p0 + nth;
        float4 m0 = lg4[p0];
        float4 m1 = lg4[p1];
        float4 a0 = u14[p0];
        float4 a1 = u14[p1];
        float z0, z1, z2, z3, z4, z5, z6, z7;
        if (tr) {
            z0 = m0.x + gum_fast(a0.x); z1 = m0.y + gum_fast(a0.y);
            z2 = m0.z + gum_fast(a0.z); z3 = m0.w + gum_fast(a0.w);
            z4 = m1.x + gum_fast(a1.x); z5 = m1.y + gum_fast(a1.y);
            z6 = m1.z + gum_fast(a1.z); z7 = m1.w + gum_fast(a1.w);
        } else {
            z0 = m0.x; z1 = m0.y; z2 = m0.z; z3 = m0.w;
            z4 = m1.x; z5 = m1.y; z6 = m1.z; z7 = m1.w;
        }
        k4[p0] = make_uint4(f2k(z0), f2k(z1), f2k(z2), f2k(z3));
        k4[p1] = make_uint4(f2k(z4), f2k(z5), f2k(z6), f2k(z7));
        atomicAdd(&h[zbin(z0)], 1u); atomicAdd(&h[zbin(z1)], 1u);
        atomicAdd(&h[zbin(z2)], 1u); atomicAdd(&h[zbin(z3)], 1u);
        atomicAdd(&h[zbin(z4)], 1u); atomicAdd(&h[zbin(z5)], 1u);
        atomicAdd(&h[zbin(z6)], 1u); atomicAdd(&h[zbin(z7)], 1u);
        p0 += 2 * nth;
    }
    if (p0 < n4) {
        float4 m0 = lg4[p0];
        float4 a0 = u14[p0];
        float z0, z1, z2, z3;
        if (tr) {
            z0 = m0.x + gum_fast(a0.x); z1 = m0.y + gum_fast(a0.y);
            z2 = m0.z + gum_fast(a0.z); z3 = m0.w + gum_fast(a0.w);
        } else { z0 = m0.x; z1 = m0.y; z2 = m0.z; z3 = m0.w; }
        k4[p0] = make_uint4(f2k(z0), f2k(z1), f2k(z2), f2k(z3));
        atomicAdd(&h[zbin(z0)], 1u); atomicAdd(&h[zbin(z1)], 1u);
        atomicAdd(&h[zbin(z2)], 1u); atomicAdd(&h[zbin(z3)], 1u);
    }
    for (int i = (n4 << 2) + blockIdx.x * NTHR + threadIdx.x; i < N; i += nth) {
        float m = lg[i], u = u1[i];
        float z = tr ? (m + gum_fast(u)) : m;
        keys[i] = f2k(z);
        atomicAdd(&h[zbin(z)], 1u);
    }
    __syncthreads();
    // merge into this block's replica: contention per line reduced NREP x
    uint32_t* rep = hist1r + (uint32_t)(blockIdx.x & (NREP - 1)) * 4096u;
    for (int b = threadIdx.x; b < 4096; b += NTHR) {
        uint32_t v = h[b];
        if (v) atomicAdd(&rep[b], v);
    }
}

// ---------- K2: sum replicas, scan 4096 bins from top, find bin b1 -> keybase ----------
__global__ void __launch_bounds__(1024) k_scan1(
        const uint32_t* __restrict__ hist1r, const int* __restrict__ kptr,
        uint32_t* __restrict__ scal) {
    __shared__ uint32_t vals[4096];
    __shared__ uint32_t cnt[1024];
    const int t = threadIdx.x;
    uint32_t loc = 0;
    for (int j = 0; j < 4; j++) {
        const int bin = 4095 - (t * 4 + j);
        uint32_t v = 0;
        #pragma unroll
        for (int r = 0; r < NREP; r++) v += hist1r[r * 4096 + bin];
        vals[t * 4 + j] = v;
        loc += v;
    }
    cnt[t] = loc;
    __syncthreads();
    for (int off = 1; off < 1024; off <<= 1) {
        uint32_t add = (t >= off) ? cnt[t - off] : 0u;
        __syncthreads();
        cnt[t] += add;
        __syncthreads();
    }
    const uint32_t K = (uint32_t)(*kptr);
    uint32_t excl = (t > 0) ? cnt[t - 1] : 0u;
    uint32_t incl = cnt[t];
    if (excl < K && K <= incl) {
        uint32_t c = excl;
        for (int j = 0; j < 4; j++) {
            uint32_t v = vals[t * 4 + j];
            if (K <= c + v) {
                int b1 = 4095 - (t * 4 + j);             // k-th element in this z-bin
                float edge = (float)b1 * ZBINW - ZMIN;   // lower z-edge, exact
                uint32_t kb = f2k(edge) - 2048u;         // margin for bin-edge fuzz
                scal[0] = kb;                            // keybase
                break;
            }
            c += v;
        }
    }
}

// ---------- K3: 1-ulp histogram of keys in [kb, kb+2^20); exact GT count ----------
__global__ void __launch_bounds__(NTHR) k_hist2(
        const uint32_t* __restrict__ keys, const uint32_t* __restrict__ scal,
        uint32_t* __restrict__ hist2, uint32_t* __restrict__ gtOut, int N) {
    __shared__ uint32_t red[NTHR];
    const uint32_t kb = scal[0];
    const uint32_t hiB = kb + (1u << 20);
    const int n4 = N >> 2;
    const int nth = gridDim.x * NTHR;
    const uint4* k4 = (const uint4*)keys;
    uint32_t gt = 0;

    int p0 = blockIdx.x * NTHR + threadIdx.x;
    while (p0 + 3 * nth < n4) {
        uint4 kk0 = k4[p0];
        uint4 kk1 = k4[p0 + nth];
        uint4 kk2 = k4[p0 + 2 * nth];
        uint4 kk3 = k4[p0 + 3 * nth];
        uint32_t ks[16] = {kk0.x, kk0.y, kk0.z, kk0.w, kk1.x, kk1.y, kk1.z, kk1.w,
                           kk2.x, kk2.y, kk2.z, kk2.w, kk3.x, kk3.y, kk3.z, kk3.w};
        #pragma unroll
        for (int j = 0; j < 16; j++) {
            uint32_t kx = ks[j];
            if (kx >= hiB) gt++;
            else if (kx >= kb) atomicAdd(&hist2[kx - kb], 1u);
        }
        p0 += 4 * nth;
    }
    while (p0 < n4) {
        uint4 kk = k4[p0];
        uint32_t ks[4] = {kk.x, kk.y, kk.z, kk.w};
        #pragma unroll
        for (int j = 0; j < 4; j++) {
            uint32_t kx = ks[j];
            if (kx >= hiB) gt++;
            else if (kx >= kb) atomicAdd(&hist2[kx - kb], 1u);
        }
        p0 += nth;
    }
    for (int i = (n4 << 2) + blockIdx.x * NTHR + threadIdx.x; i < N; i += nth) {
        uint32_t kx = keys[i];
        if (kx >= hiB) gt++;
        else if (kx >= kb) atomicAdd(&hist2[kx - kb], 1u);
    }
    red[threadIdx.x] = gt;
    __syncthreads();
    for (int off = NTHR / 2; off; off >>= 1) {
        if (threadIdx.x < off) red[threadIdx.x] += red[threadIdx.x + off];
        __syncthreads();
    }
    if (threadIdx.x == 0 && red[0]) atomicAdd(gtOut, red[0]);
}

// ---------- K4a: chunk partial sums of hist2 (1024 chunks of 1024) ----------
__global__ void __launch_bounds__(NTHR) k_part(
        const uint32_t* __restrict__ hist2, uint32_t* __restrict__ part) {
    __shared__ uint32_t red[NTHR];
    uint32_t sum = 0;
    const int base = blockIdx.x << 10;
    for (int j = threadIdx.x; j < 1024; j += NTHR) sum += hist2[base + j];
    red[threadIdx.x] = sum;
    __syncthreads();
    for (int off = NTHR / 2; off; off >>= 1) {
        if (threadIdx.x < off) red[threadIdx.x] += red[threadIdx.x + off];
        __syncthreads();
    }
    if (threadIdx.x == 0) part[blockIdx.x] = red[0];
}

// ---------- K4b: exact threshold offset, window [klo,khi], count above window ----------
__global__ void __launch_bounds__(1024) k_scan2(
        const uint32_t* __restrict__ hist2, const uint32_t* __restrict__ part,
        const int* __restrict__ kptr, uint32_t* __restrict__ scal) {
    __shared__ uint32_t cs[1024];
    __shared__ uint32_t bs[1024];
    __shared__ uint32_t red[1024];
    __shared__ int shI[4];
    const int t = threadIdx.x;
    const uint32_t kb = scal[0];
    const uint32_t GT = scal[1];
    const uint32_t kk1 = (uint32_t)(*kptr) - GT;

    cs[t] = part[1023 - t];
    __syncthreads();
    for (int off = 1; off < 1024; off <<= 1) {
        uint32_t add = (t >= off) ? cs[t - off] : 0u;
        __syncthreads();
        cs[t] += add;
        __syncthreads();
    }
    {
        uint32_t excl = t ? cs[t - 1] : 0u;
        if (excl < kk1 && kk1 <= cs[t]) shI[0] = t;
    }
    __syncthreads();
    const int rp = shI[0];
    const int jc = 1023 - rp;
    const uint32_t gt_chunks = rp ? cs[rp - 1] : 0u;
    const uint32_t kk_in = kk1 - gt_chunks;

    bs[t] = hist2[(jc << 10) + (1023 - t)];
    __syncthreads();
    for (int off = 1; off < 1024; off <<= 1) {
        uint32_t add = (t >= off) ? bs[t - off] : 0u;
        __syncthreads();
        bs[t] += add;
        __syncthreads();
    }
    {
        uint32_t excl = t ? bs[t - 1] : 0u;
        if (excl < kk_in && kk_in <= bs[t]) shI[1] = t;
    }
    __syncthreads();
    const int rq = shI[1];
    const int b2 = (jc << 10) + (1023 - rq);

    int W = 64;
    int lo = 0, hi = 0;
    uint32_t caw = 0;
    while (true) {
        lo = b2 - W; if (lo < 0) lo = 0;
        hi = b2 + W; if (hi > 0xFFFFF) hi = 0xFFFFF;
        uint32_t v = 0;
        for (int b = lo + t; b <= hi; b += 1024) v += hist2[b];
        red[t] = v;
        __syncthreads();
        for (int off = 512; off; off >>= 1) {
            if (t < off) red[t] += red[t + off];
            __syncthreads();
        }
        uint32_t nW = red[0];
        __syncthreads();
        if (nW <= 3500u || W == 0) {
            const int ch = hi >> 10;
            const int chend = (ch << 10) + 1023;
            uint32_t v2 = 0;
            for (int b = hi + 1 + t; b <= chend; b += 1024) v2 += hist2[b];
            red[t] = v2;
            __syncthreads();
            for (int off = 512; off; off >>= 1) {
                if (t < off) red[t] += red[t + off];
                __syncthreads();
            }
            uint32_t inpart = red[0];
            __syncthreads();
            const int rpch = 1023 - ch;
            const uint32_t sufExcl = rpch ? cs[rpch - 1] : 0u;
            caw = GT + sufExcl + inpart;
            break;
        }
        W >>= 1;
    }
    if (t == 0) {
        scal[3] = kb + (uint32_t)lo;  // klo
        scal[4] = kb + (uint32_t)hi;  // khi
        scal[5] = caw;
    }
}

// ---------- K5: final pass — ratio-trick decisions, collect window candidates ----------
// u2 is INTERLEAVED: pair for element i is (u2[2i], u2[2i+1]).
__global__ void __launch_bounds__(NTHR) k_final(
        uint32_t* __restrict__ keys /* == (uint32_t*)d_out */,
        const float* __restrict__ u2, const int* __restrict__ trainp,
        const uint32_t* __restrict__ scal,
        uint32_t* __restrict__ candIdx, uint32_t* __restrict__ candCount, int N) {
    const uint32_t klo = scal[3], khi = scal[4];
    const int tr = *trainp;
    const int n4 = N >> 2;
    const int nth = gridDim.x * NTHR;
    const uint4* kr4 = (const uint4*)keys;
    const float4* u24 = (const float4*)u2;
    float* outf = (float*)keys;

    int p0 = blockIdx.x * NTHR + threadIdx.x;
    while (p0 + nth < n4) {
        const int p1 = p0 + nth;
        uint4 kk0 = kr4[p0];
        uint4 kk1 = kr4[p1];
        float4 ua0, ub0, ua1, ub1;
        if (tr) {
            ua0 = u24[2 * p0]; ub0 = u24[2 * p0 + 1];
            ua1 = u24[2 * p1]; ub1 = u24[2 * p1 + 1];
        }
        uint32_t ks[8] = {kk0.x, kk0.y, kk0.z, kk0.w, kk1.x, kk1.y, kk1.z, kk1.w};
        float uu[16];
        if (tr) {
            uu[0] = ua0.x; uu[1] = ua0.y; uu[2] = ua0.z; uu[3] = ua0.w;
            uu[4] = ub0.x; uu[5] = ub0.y; uu[6] = ub0.z; uu[7] = ub0.w;
            uu[8] = ua1.x; uu[9] = ua1.y; uu[10] = ua1.z; uu[11] = ua1.w;
            uu[12] = ub1.x; uu[13] = ub1.y; uu[14] = ub1.z; uu[15] = ub1.w;
        }
        float res[8];
        bool inw[8];
        bool anyw = false;
        #pragma unroll
        for (int j = 0; j < 8; j++) {
            inw[j] = (ks[j] >= klo) && (ks[j] <= khi);
            anyw |= inw[j];
        }
        #pragma unroll
        for (int j = 0; j < 8; j++) {
            const int half = j >> 2, e = j & 3;
            float mv = (ks[j] > khi) ? 1.0f : 0.0f;
            float ua = uu[half * 8 + 2 * e];
            float ub = uu[half * 8 + 2 * e + 1];
            res[j] = (tr && !inw[j]) ? decide_fast(mv, ua, ub) : mv;
        }
        if (!anyw) {
            ((float4*)outf)[p0] = make_float4(res[0], res[1], res[2], res[3]);
            ((float4*)outf)[p1] = make_float4(res[4], res[5], res[6], res[7]);
        } else {
            #pragma unroll
            for (int j = 0; j < 8; j++) {
                const int idx = ((j < 4) ? p0 : p1) * 4 + (j & 3);
                if (inw[j]) {
                    uint32_t p = atomicAdd(candCount, 1u);
                    if (p < CAND_CAP) candIdx[p] = (uint32_t)idx;
                } else {
                    outf[idx] = res[j];
                }
            }
        }
        p0 += 2 * nth;
    }
    if (p0 < n4) {
        uint4 kk = kr4[p0];
        float4 ua, ub;
        if (tr) { ua = u24[2 * p0]; ub = u24[2 * p0 + 1]; }
        uint32_t ks[4] = {kk.x, kk.y, kk.z, kk.w};
        float pa[4] = {ua.x, ua.z, ub.x, ub.z};
        float pb[4] = {ua.y, ua.w, ub.y, ub.w};
        #pragma unroll
        for (int j = 0; j < 4; j++) {
            uint32_t kx = ks[j];
            if (kx >= klo && kx <= khi) {
                uint32_t p = atomicAdd(candCount, 1u);
                if (p < CAND_CAP) candIdx[p] = (uint32_t)(4 * p0 + j);
            } else {
                float mv = (kx > khi) ? 1.0f : 0.0f;
                outf[4 * p0 + j] = tr ? decide_fast(mv, pa[j], pb[j]) : mv;
            }
        }
    }
    for (int i = (n4 << 2) + blockIdx.x * NTHR + threadIdx.x; i < N; i += nth) {
        uint32_t kx = keys[i];
        if (kx >= klo && kx <= khi) {
            uint32_t p = atomicAdd(candCount, 1u);
            if (p < CAND_CAP) candIdx[p] = (uint32_t)i;
            continue;
        }
        float mv = (kx > khi) ? 1.0f : 0.0f;
        outf[i] = tr ? decide_fast(mv, u2[2 * i], u2[2 * i + 1]) : mv;
    }
}

// ---------- K6: refine window candidates exactly (CR log, sort, select) ----------
__global__ void __launch_bounds__(NTHR) k_refine(
        const float* __restrict__ lg, const float* __restrict__ u1,
        const float* __restrict__ u2, const int* __restrict__ kptr,
        const int* __restrict__ trainp, const uint32_t* __restrict__ scal,
        const uint32_t* __restrict__ candIdx, const uint32_t* __restrict__ candCount,
        float* __restrict__ out) {
    __shared__ float zs[CAND_CAP];
    __shared__ int is[CAND_CAP];
    const int tr = *trainp;
    int n = (int)(*candCount);
    if (n > CAND_CAP) n = CAND_CAP;
    int npow2 = 64;
    while (npow2 < n) npow2 <<= 1;

    for (int e = threadIdx.x; e < npow2; e += NTHR) {
        if (e < n) {
            int i = (int)candIdx[e];
            float m = lg[i];
            zs[e] = tr ? (m + gum_cr(u1[i])) : m;
            is[e] = i;
        } else {
            zs[e] = -INFINITY;
            is[e] = 0x40000000 + e;
        }
    }
    __syncthreads();

    for (int size = 2; size <= npow2; size <<= 1) {
        for (int str = size >> 1; str > 0; str >>= 1) {
            for (int e = threadIdx.x; e < npow2; e += NTHR) {
                int p = e ^ str;
                if (p > e) {
                    float za = zs[e], zb = zs[p];
                    int ia = is[e], ib = is[p];
                    bool aBefore = (za > zb) || (za == zb && ia < ib);
                    bool descBlock = ((e & size) == 0);
                    if (descBlock ? !aBefore : aBefore) {
                        zs[e] = zb; zs[p] = za;
                        is[e] = ib; is[p] = ia;
                    }
                }
            }
            __syncthreads();
        }
    }

    const int K = *kptr;
    const int caw = (int)scal[5];
    const int R = K - caw;
    for (int e = threadIdx.x; e < n; e += NTHR) {
        int i = is[e];
        float mv = (e < R) ? 1.0f : 0.0f;
        out[i] = tr ? decide_cr(mv, u2[2 * i], u2[2 * i + 1]) : mv;
    }
}

// ---------- launcher ----------
extern "C" void kernel_launch(void* const* d_in, const int* in_sizes, int n_in,
                              void* d_out, int out_size, void* d_ws, size_t ws_size,
                              hipStream_t stream) {
    const float* lg = (const float*)d_in[0];
    const float* u1 = (const float*)d_in[1];
    const float* u2 = (const float*)d_in[2];
    const int* kptr = (const int*)d_in[3];
    const int* trainp = (const int*)d_in[4];
    float* out = (float*)d_out;
    const int N = in_sizes[0];

    uint32_t* keys = (uint32_t*)d_out;   // staged in d_out, overwritten by results

    // workspace (~4.7 MB)
    uint32_t* hist1r = (uint32_t*)d_ws;          // NREP * 4096
    uint32_t* hist2 = hist1r + NREP * 4096;      // 1<<20
    uint32_t* part = hist2 + (1u << 20);         // 1024
    uint32_t* scal = part + 1024;                // 16
    uint32_t* candCount = scal + 16;             // 1
    uint32_t* candIdx = candCount + 1;           // CAND_CAP

    k_zero<<<dim3(2048), dim3(NTHR), 0, stream>>>(hist1r, hist2, scal, candCount);
    k_keys<<<dim3(GRID_KEYS), dim3(NTHR), 0, stream>>>(lg, u1, trainp, keys, hist1r, N);
    k_scan1<<<dim3(1), dim3(1024), 0, stream>>>(hist1r, kptr, scal);
    k_hist2<<<dim3(GRID_H2), dim3(NTHR), 0, stream>>>(keys, scal, hist2, &scal[1], N);
    k_part<<<dim3(GRID_PART), dim3(NTHR), 0, stream>>>(hist2, part);
    k_scan2<<<dim3(1), dim3(1024), 0, stream>>>(hist2, part, kptr, scal);
    k_final<<<dim3(GRID_FIN), dim3(NTHR), 0, stream>>>(keys, u2, trainp, scal,
                                                       candIdx, candCount, N);
    k_refine<<<dim3(1), dim3(NTHR), 0, stream>>>(lg, u1, u2, kptr, trainp, scal,
                                                 candIdx, candCount, out);
}

// Round 9
// 164.645 us; speedup vs baseline: 4.9282x; 1.1128x over previous
//
#include <hip/hip_runtime.h>
#include <hip/hip_bf16.h>
#include <math.h>
#include <cstdint>

#define FEPS 1e-8f
#define NTHR 256
#define CAND_CAP 4096
#define NREP 32            // replicated coarse histograms

#define GRID_KEYS 2048
#define GRID_H2   2048
#define GRID_FIN  2048
#define GRID_PART 1024

// linear-z binning for pass 1: 4096 bins over [-8, 24), width 1/128
#define ZMIN 8.0f
#define ZSCALE 128.0f
#define ZBINW 0.0078125f   // 1/128, exact in f32

// ---------- numeric helpers ----------

__device__ __forceinline__ uint32_t f2k(float f) {
    uint32_t b = __float_as_uint(f);
    return (b & 0x80000000u) ? ~b : (b | 0x80000000u);
}

__device__ __forceinline__ float gum_fast(float u) {
    float t = u + FEPS;
    float a = logf(t);
    float w = -a + FEPS;
    float d = logf(w);
    return -d;
}

__device__ __forceinline__ float logCR(float x) {
    return (float)log((double)x);
}
__device__ __forceinline__ float gum_cr(float u) {
    float t = u + FEPS;
    float a = logCR(t);
    float w = -a + FEPS;
    float d = logCR(w);
    return -d;
}

// exact decision: out = 1 iff RN(v1 - v0) > 2^-25
__device__ __forceinline__ float decide_cr(float maskv, float ua, float ub) {
    float G0 = gum_cr(ua);
    float G1 = gum_cr(ub);
    float V1 = maskv + G1;
    float diff = V1 - G0;
    return (diff > 0x1p-25f) ? 1.0f : 0.0f;
}

// ratio trick: out=1 iff w0 > exp(2^-25-mv)*w1; CR fallback in 1e-4 band
__device__ __forceinline__ float decide_fast(float mv, float ua, float ub) {
    float w0 = -logf(ua + FEPS) + FEPS;
    float w1 = -logf(ub + FEPS) + FEPS;
    float T = (mv != 0.0f) ? 0.36787944f : 1.0f;
    float rhs = T * w1;
    float q = w0 - rhs;
    if (fabsf(q) > 1e-4f * rhs) return (q > 0.0f) ? 1.0f : 0.0f;
    return decide_cr(mv, ua, ub);
}

__device__ __forceinline__ int zbin(float z) {
    float t = (z + ZMIN) * ZSCALE;
    int b = (int)t;
    if (b < 0) b = 0;
    if (b > 4095) b = 4095;
    return b;
}

// ---------- K0: zero workspace ----------
__global__ void k_zero(uint32_t* __restrict__ hist1r, uint32_t* __restrict__ hist2,
                       uint32_t* __restrict__ scal, uint32_t* __restrict__ candCount) {
    int i = blockIdx.x * blockDim.x + threadIdx.x;
    int stride = gridDim.x * blockDim.x;
    for (int b = i; b < NREP * 4096; b += stride) hist1r[b] = 0u;
    for (int b = i; b < (1 << 20); b += stride) hist2[b] = 0u;
    if (i < 16) scal[i] = 0u;
    if (i == 0) *candCount = 0u;
}

// ---------- K1: keys (into d_out) + LDS hist -> replicated global merge ----------
// (R8 version: best measured k_keys config, <=74.5 us)
__global__ void __launch_bounds__(NTHR) k_keys(
        const float* __restrict__ lg, const float* __restrict__ u1,
        const int* __restrict__ trainp, uint32_t* __restrict__ keys,
        uint32_t* __restrict__ hist1r, int N) {
    __shared__ uint32_t h[4096];
    for (int b = threadIdx.x; b < 4096; b += NTHR) h[b] = 0u;
    __syncthreads();
    const int tr = *trainp;
    const int n4 = N >> 2;
    const int nth = gridDim.x * NTHR;
    const float4* lg4 = (const float4*)lg;
    const float4* u14 = (const float4*)u1;
    uint4* k4 = (uint4*)keys;

    int p0 = blockIdx.x * NTHR + threadIdx.x;
    while (p0 + nth < n4) {
        const int p1 = p0 + nth;
        float4 m0 = lg4[p0];
        float4 m1 = lg4[p1];
        float4 a0 = u14[p0];
        float4 a1 = u14[p1];
        float z0, z1, z2, z3, z4, z5, z6, z7;
        if (tr) {
            z0 = m0.x + gum_fast(a0.x); z1 = m0.y + gum_fast(a0.y);
            z2 = m0.z + gum_fast(a0.z); z3 = m0.w + gum_fast(a0.w);
            z4 = m1.x + gum_fast(a1.x); z5 = m1.y + gum_fast(a1.y);
            z6 = m1.z + gum_fast(a1.z); z7 = m1.w + gum_fast(a1.w);
        } else {
            z0 = m0.x; z1 = m0.y; z2 = m0.z; z3 = m0.w;
            z4 = m1.x; z5 = m1.y; z6 = m1.z; z7 = m1.w;
        }
        k4[p0] = make_uint4(f2k(z0), f2k(z1), f2k(z2), f2k(z3));
        k4[p1] = make_uint4(f2k(z4), f2k(z5), f2k(z6), f2k(z7));
        atomicAdd(&h[zbin(z0)], 1u); atomicAdd(&h[zbin(z1)], 1u);
        atomicAdd(&h[zbin(z2)], 1u); atomicAdd(&h[zbin(z3)], 1u);
        atomicAdd(&h[zbin(z4)], 1u); atomicAdd(&h[zbin(z5)], 1u);
        atomicAdd(&h[zbin(z6)], 1u); atomicAdd(&h[zbin(z7)], 1u);
        p0 += 2 * nth;
    }
    if (p0 < n4) {
        float4 m0 = lg4[p0];
        float4 a0 = u14[p0];
        float z0, z1, z2, z3;
        if (tr) {
            z0 = m0.x + gum_fast(a0.x); z1 = m0.y + gum_fast(a0.y);
            z2 = m0.z + gum_fast(a0.z); z3 = m0.w + gum_fast(a0.w);
        } else { z0 = m0.x; z1 = m0.y; z2 = m0.z; z3 = m0.w; }
        k4[p0] = make_uint4(f2k(z0), f2k(z1), f2k(z2), f2k(z3));
        atomicAdd(&h[zbin(z0)], 1u); atomicAdd(&h[zbin(z1)], 1u);
        atomicAdd(&h[zbin(z2)], 1u); atomicAdd(&h[zbin(z3)], 1u);
    }
    for (int i = (n4 << 2) + blockIdx.x * NTHR + threadIdx.x; i < N; i += nth) {
        float m = lg[i], u = u1[i];
        float z = tr ? (m + gum_fast(u)) : m;
        keys[i] = f2k(z);
        atomicAdd(&h[zbin(z)], 1u);
    }
    __syncthreads();
    uint32_t* rep = hist1r + (uint32_t)(blockIdx.x & (NREP - 1)) * 4096u;
    for (int b = threadIdx.x; b < 4096; b += NTHR) {
        uint32_t v = h[b];
        if (v) atomicAdd(&rep[b], v);
    }
}

// ---------- K2: sum replicas, scan 4096 bins from top, find bin b1 -> keybase ----------
__global__ void __launch_bounds__(1024) k_scan1(
        const uint32_t* __restrict__ hist1r, const int* __restrict__ kptr,
        uint32_t* __restrict__ scal) {
    __shared__ uint32_t vals[4096];
    __shared__ uint32_t cnt[1024];
    const int t = threadIdx.x;
    uint32_t loc = 0;
    for (int j = 0; j < 4; j++) {
        const int bin = 4095 - (t * 4 + j);
        uint32_t v = 0;
        #pragma unroll
        for (int r = 0; r < NREP; r++) v += hist1r[r * 4096 + bin];
        vals[t * 4 + j] = v;
        loc += v;
    }
    cnt[t] = loc;
    __syncthreads();
    for (int off = 1; off < 1024; off <<= 1) {
        uint32_t add = (t >= off) ? cnt[t - off] : 0u;
        __syncthreads();
        cnt[t] += add;
        __syncthreads();
    }
    const uint32_t K = (uint32_t)(*kptr);
    uint32_t excl = (t > 0) ? cnt[t - 1] : 0u;
    uint32_t incl = cnt[t];
    if (excl < K && K <= incl) {
        uint32_t c = excl;
        for (int j = 0; j < 4; j++) {
            uint32_t v = vals[t * 4 + j];
            if (K <= c + v) {
                int b1 = 4095 - (t * 4 + j);             // k-th element in this z-bin
                float edge = (float)b1 * ZBINW - ZMIN;   // lower z-edge, exact
                uint32_t kb = f2k(edge) - 2048u;         // margin for bin-edge fuzz
                scal[0] = kb;                            // keybase
                break;
            }
            c += v;
        }
    }
}

// ---------- K3: 1-ulp histogram of keys in [kb, kb+2^20); exact GT count ----------
// (R1/R2 loop shape: simple grid-stride, grid 2048)
__global__ void __launch_bounds__(NTHR) k_hist2(
        const uint32_t* __restrict__ keys, const uint32_t* __restrict__ scal,
        uint32_t* __restrict__ hist2, uint32_t* __restrict__ gtOut, int N) {
    __shared__ uint32_t red[NTHR];
    const uint32_t kb = scal[0];
    const uint32_t hiB = kb + (1u << 20);
    const int n4 = N >> 2;
    const int tid = blockIdx.x * NTHR + threadIdx.x;
    const int stride = gridDim.x * NTHR;
    const uint4* k4 = (const uint4*)keys;
    uint32_t gt = 0;
    for (int i = tid; i < n4; i += stride) {
        uint4 kk = k4[i];
        uint32_t ks[4] = {kk.x, kk.y, kk.z, kk.w};
        #pragma unroll
        for (int j = 0; j < 4; j++) {
            uint32_t kx = ks[j];
            if (kx >= hiB) gt++;
            else if (kx >= kb) atomicAdd(&hist2[kx - kb], 1u);
        }
    }
    for (int i = (n4 << 2) + tid; i < N; i += stride) {
        uint32_t kx = keys[i];
        if (kx >= hiB) gt++;
        else if (kx >= kb) atomicAdd(&hist2[kx - kb], 1u);
    }
    red[threadIdx.x] = gt;
    __syncthreads();
    for (int off = NTHR / 2; off; off >>= 1) {
        if (threadIdx.x < off) red[threadIdx.x] += red[threadIdx.x + off];
        __syncthreads();
    }
    if (threadIdx.x == 0 && red[0]) atomicAdd(gtOut, red[0]);
}

// ---------- K4a: chunk partial sums of hist2 (1024 chunks of 1024) ----------
__global__ void __launch_bounds__(NTHR) k_part(
        const uint32_t* __restrict__ hist2, uint32_t* __restrict__ part) {
    __shared__ uint32_t red[NTHR];
    uint32_t sum = 0;
    const int base = blockIdx.x << 10;
    for (int j = threadIdx.x; j < 1024; j += NTHR) sum += hist2[base + j];
    red[threadIdx.x] = sum;
    __syncthreads();
    for (int off = NTHR / 2; off; off >>= 1) {
        if (threadIdx.x < off) red[threadIdx.x] += red[threadIdx.x + off];
        __syncthreads();
    }
    if (threadIdx.x == 0) part[blockIdx.x] = red[0];
}

// ---------- K4b: exact threshold offset, window [klo,khi], count above window ----------
__global__ void __launch_bounds__(1024) k_scan2(
        const uint32_t* __restrict__ hist2, const uint32_t* __restrict__ part,
        const int* __restrict__ kptr, uint32_t* __restrict__ scal) {
    __shared__ uint32_t cs[1024];
    __shared__ uint32_t bs[1024];
    __shared__ uint32_t red[1024];
    __shared__ int shI[4];
    const int t = threadIdx.x;
    const uint32_t kb = scal[0];
    const uint32_t GT = scal[1];
    const uint32_t kk1 = (uint32_t)(*kptr) - GT;

    cs[t] = part[1023 - t];
    __syncthreads();
    for (int off = 1; off < 1024; off <<= 1) {
        uint32_t add = (t >= off) ? cs[t - off] : 0u;
        __syncthreads();
        cs[t] += add;
        __syncthreads();
    }
    {
        uint32_t excl = t ? cs[t - 1] : 0u;
        if (excl < kk1 && kk1 <= cs[t]) shI[0] = t;
    }
    __syncthreads();
    const int rp = shI[0];
    const int jc = 1023 - rp;
    const uint32_t gt_chunks = rp ? cs[rp - 1] : 0u;
    const uint32_t kk_in = kk1 - gt_chunks;

    bs[t] = hist2[(jc << 10) + (1023 - t)];
    __syncthreads();
    for (int off = 1; off < 1024; off <<= 1) {
        uint32_t add = (t >= off) ? bs[t - off] : 0u;
        __syncthreads();
        bs[t] += add;
        __syncthreads();
    }
    {
        uint32_t excl = t ? bs[t - 1] : 0u;
        if (excl < kk_in && kk_in <= bs[t]) shI[1] = t;
    }
    __syncthreads();
    const int rq = shI[1];
    const int b2 = (jc << 10) + (1023 - rq);

    int W = 64;
    int lo = 0, hi = 0;
    uint32_t caw = 0;
    while (true) {
        lo = b2 - W; if (lo < 0) lo = 0;
        hi = b2 + W; if (hi > 0xFFFFF) hi = 0xFFFFF;
        uint32_t v = 0;
        for (int b = lo + t; b <= hi; b += 1024) v += hist2[b];
        red[t] = v;
        __syncthreads();
        for (int off = 512; off; off >>= 1) {
            if (t < off) red[t] += red[t + off];
            __syncthreads();
        }
        uint32_t nW = red[0];
        __syncthreads();
        if (nW <= 3500u || W == 0) {
            const int ch = hi >> 10;
            const int chend = (ch << 10) + 1023;
            uint32_t v2 = 0;
            for (int b = hi + 1 + t; b <= chend; b += 1024) v2 += hist2[b];
            red[t] = v2;
            __syncthreads();
            for (int off = 512; off; off >>= 1) {
                if (t < off) red[t] += red[t + off];
                __syncthreads();
            }
            uint32_t inpart = red[0];
            __syncthreads();
            const int rpch = 1023 - ch;
            const uint32_t sufExcl = rpch ? cs[rpch - 1] : 0u;
            caw = GT + sufExcl + inpart;
            break;
        }
        W >>= 1;
    }
    if (t == 0) {
        scal[3] = kb + (uint32_t)lo;  // klo
        scal[4] = kb + (uint32_t)hi;  // khi
        scal[5] = caw;
    }
}

// ---------- K5: final pass (R1 loop shape, grid 2048) + ratio-trick decide ----------
// u2 INTERLEAVED: pair for element i is (u2[2i], u2[2i+1]); for uint4-position i,
// uu[] = {a0,b0,a1,b1,a2,b2,a3,b3}; element j uses (uu[2j], uu[2j+1]).
__global__ void __launch_bounds__(NTHR) k_final(
        uint32_t* __restrict__ keys /* == (uint32_t*)d_out */,
        const float* __restrict__ u2, const int* __restrict__ trainp,
        const uint32_t* __restrict__ scal,
        uint32_t* __restrict__ candIdx, uint32_t* __restrict__ candCount, int N) {
    const uint32_t klo = scal[3], khi = scal[4];
    const int tr = *trainp;
    const int n4 = N >> 2;
    const int tid = blockIdx.x * NTHR + threadIdx.x;
    const int stride = gridDim.x * NTHR;
    const uint4* kr4 = (const uint4*)keys;
    const float4* u24 = (const float4*)u2;
    float* outf = (float*)keys;

    for (int i = tid; i < n4; i += stride) {
        uint4 kk = kr4[i];
        uint32_t ks[4] = {kk.x, kk.y, kk.z, kk.w};
        float uu[8];
        if (tr) {
            float4 ua = u24[2 * i];
            float4 ub = u24[2 * i + 1];
            uu[0] = ua.x; uu[1] = ua.y; uu[2] = ua.z; uu[3] = ua.w;
            uu[4] = ub.x; uu[5] = ub.y; uu[6] = ub.z; uu[7] = ub.w;
        }
        float res[4];
        bool inw[4];
        bool anyw = false;
        #pragma unroll
        for (int j = 0; j < 4; j++) {
            inw[j] = (ks[j] >= klo) && (ks[j] <= khi);
            anyw |= inw[j];
        }
        #pragma unroll
        for (int j = 0; j < 4; j++) {
            float mv = (ks[j] > khi) ? 1.0f : 0.0f;
            res[j] = (tr && !inw[j]) ? decide_fast(mv, uu[2 * j], uu[2 * j + 1]) : mv;
        }
        if (!anyw) {
            ((float4*)outf)[i] = make_float4(res[0], res[1], res[2], res[3]);
        } else {
            #pragma unroll
            for (int j = 0; j < 4; j++) {
                if (inw[j]) {
                    uint32_t p = atomicAdd(candCount, 1u);
                    if (p < CAND_CAP) candIdx[p] = (uint32_t)(4 * i + j);
                } else {
                    outf[4 * i + j] = res[j];
                }
            }
        }
    }
    for (int i = (n4 << 2) + tid; i < N; i += stride) {  // tail
        uint32_t kx = keys[i];
        if (kx >= klo && kx <= khi) {
            uint32_t p = atomicAdd(candCount, 1u);
            if (p < CAND_CAP) candIdx[p] = (uint32_t)i;
            continue;
        }
        float mv = (kx > khi) ? 1.0f : 0.0f;
        outf[i] = tr ? decide_fast(mv, u2[2 * i], u2[2 * i + 1]) : mv;
    }
}

// ---------- K6: refine window candidates exactly (CR log, sort, select) ----------
__global__ void __launch_bounds__(NTHR) k_refine(
        const float* __restrict__ lg, const float* __restrict__ u1,
        const float* __restrict__ u2, const int* __restrict__ kptr,
        const int* __restrict__ trainp, const uint32_t* __restrict__ scal,
        const uint32_t* __restrict__ candIdx, const uint32_t* __restrict__ candCount,
        float* __restrict__ out) {
    __shared__ float zs[CAND_CAP];
    __shared__ int is[CAND_CAP];
    const int tr = *trainp;
    int n = (int)(*candCount);
    if (n > CAND_CAP) n = CAND_CAP;
    int npow2 = 64;
    while (npow2 < n) npow2 <<= 1;

    for (int e = threadIdx.x; e < npow2; e += NTHR) {
        if (e < n) {
            int i = (int)candIdx[e];
            float m = lg[i];
            zs[e] = tr ? (m + gum_cr(u1[i])) : m;
            is[e] = i;
        } else {
            zs[e] = -INFINITY;
            is[e] = 0x40000000 + e;
        }
    }
    __syncthreads();

    for (int size = 2; size <= npow2; size <<= 1) {
        for (int str = size >> 1; str > 0; str >>= 1) {
            for (int e = threadIdx.x; e < npow2; e += NTHR) {
                int p = e ^ str;
                if (p > e) {
                    float za = zs[e], zb = zs[p];
                    int ia = is[e], ib = is[p];
                    bool aBefore = (za > zb) || (za == zb && ia < ib);
                    bool descBlock = ((e & size) == 0);
                    if (descBlock ? !aBefore : aBefore) {
                        zs[e] = zb; zs[p] = za;
                        is[e] = ib; is[p] = ia;
                    }
                }
            }
            __syncthreads();
        }
    }

    const int K = *kptr;
    const int caw = (int)scal[5];
    const int R = K - caw;
    for (int e = threadIdx.x; e < n; e += NTHR) {
        int i = is[e];
        float mv = (e < R) ? 1.0f : 0.0f;
        out[i] = tr ? decide_cr(mv, u2[2 * i], u2[2 * i + 1]) : mv;
    }
}

// ---------- launcher ----------
extern "C" void kernel_launch(void* const* d_in, const int* in_sizes, int n_in,
                              void* d_out, int out_size, void* d_ws, size_t ws_size,
                              hipStream_t stream) {
    const float* lg = (const float*)d_in[0];
    const float* u1 = (const float*)d_in[1];
    const float* u2 = (const float*)d_in[2];
    const int* kptr = (const int*)d_in[3];
    const int* trainp = (const int*)d_in[4];
    float* out = (float*)d_out;
    const int N = in_sizes[0];

    uint32_t* keys = (uint32_t*)d_out;   // staged in d_out, overwritten by results

    // workspace (~4.7 MB)
    uint32_t* hist1r = (uint32_t*)d_ws;          // NREP * 4096
    uint32_t* hist2 = hist1r + NREP * 4096;      // 1<<20
    uint32_t* part = hist2 + (1u << 20);         // 1024
    uint32_t* scal = part + 1024;                // 16
    uint32_t* candCount = scal + 16;             // 1
    uint32_t* candIdx = candCount + 1;           // CAND_CAP

    k_zero<<<dim3(1024), dim3(NTHR), 0, stream>>>(hist1r, hist2, scal, candCount);
    k_keys<<<dim3(GRID_KEYS), dim3(NTHR), 0, stream>>>(lg, u1, trainp, keys, hist1r, N);
    k_scan1<<<dim3(1), dim3(1024), 0, stream>>>(hist1r, kptr, scal);
    k_hist2<<<dim3(GRID_H2), dim3(NTHR), 0, stream>>>(keys, scal, hist2, &scal[1], N);
    k_part<<<dim3(GRID_PART), dim3(NTHR), 0, stream>>>(hist2, part);
    k_scan2<<<dim3(1), dim3(1024), 0, stream>>>(hist2, part, kptr, scal);
    k_final<<<dim3(GRID_FIN), dim3(NTHR), 0, stream>>>(keys, u2, trainp, scal,
                                                       candIdx, candCount, N);
    k_refine<<<dim3(1), dim3(NTHR), 0, stream>>>(lg, u1, u2, kptr, trainp, scal,
                                                 candIdx, candCount, out);
}